// Round 1
// baseline (197.055 us; speedup 1.0000x reference)
//
#include <hip/hip_runtime.h>

// BlockSparseFlashAttention — Phi-3-small blocksparse prefill, MI355X (gfx950)
// S=2048, H=32, HKV=8 (GQA x4), D=128, BLK=64, LOCAL=16, VERT=8, HEAD_SLIDE=1
//
// R7. Counters said latency-serialized (Mfma 18%, VALU 27%, Occ 15%), not BW.
// Restructure:
//  - qt=4: one wave owns a full 64-row query block -> wave-tile count halves,
//    LDS bytes per MFMA halve (each wave reads full K/V tile regardless of qt).
//  - 4 waves/block, qb set {x,15-x,16+x,31-x}: constant ~52 wave-tiles/block,
//    grid 256 = exactly 1 block/CU, kvh=blk&7 XCD pin kept.
//  - double-buffered K/V, ONE barrier per tile: stage(t+1) -> compute(t) ->
//    __syncthreads. DMA latency hides under the ~1500-cycle compute phase
//    (guide's minimum 2-phase pipeline) instead of being drained cold.
//  - P (C-layout -> B-operand) transform in registers: cvt_pk_bf16 +
//    permlane32_swap/permlane16_swap quad-gathers + hi32 select. Deletes the
//    P LDS overlay (16 KB/wave-tile traffic + an lgkm sync point), LDS=64KB.
//  - no-max exp2-domain softmax + l-via-ones-MFMA kept (validated R4-R6).

typedef __bf16 bf16_t;
typedef __bf16 bf16x4 __attribute__((ext_vector_type(4)));
typedef __bf16 bf16x8 __attribute__((ext_vector_type(8)));
typedef float  fx4    __attribute__((ext_vector_type(4)));
typedef unsigned u32x2 __attribute__((ext_vector_type(2)));
typedef unsigned u32x4 __attribute__((ext_vector_type(4)));

#define SL2E_F 0.1275240614354876f   // (1/sqrt(128)) * log2(e)

__device__ inline void load_lds16(const bf16_t* g, bf16_t* l) {
    __builtin_amdgcn_global_load_lds(
        (const __attribute__((address_space(1))) void*)g,
        (__attribute__((address_space(3))) void*)l, 16, 0, 0);
}

__device__ inline unsigned cvt_pk_bf16(float lo, float hi) {
    unsigned r;
    asm("v_cvt_pk_bf16_f32 %0, %1, %2" : "=v"(r) : "v"(lo), "v"(hi));
    return r;
}

// Returns the two quad-gathers of A (quads = 16-lane groups):
//   ret[0] lane(q,c) = A[ (q&1 ? 2 : 0)*16 + c ]   -> pattern {0,2,0,2}
//   ret[1] lane(q,c) = A[ (q&1 ? 3 : 1)*16 + c ]   -> pattern {1,3,1,3}
__device__ inline u32x2 quad_gather(unsigned A) {
    u32x2 bc = __builtin_amdgcn_permlane32_swap(A, A, false, false);
    // bc[0] = {A.q0,A.q1,A.q0,A.q1}, bc[1] = {A.q2,A.q3,A.q2,A.q3}
    return __builtin_amdgcn_permlane16_swap(bc[0], bc[1], false, false);
    // ret[0] = {A.q0,A.q2,A.q0,A.q2}, ret[1] = {A.q1,A.q3,A.q1,A.q3}
}

// ---- fused pre-pass: K fp32->bf16 (same layout) + V -> V^T bf16 ----------
__global__ void prep_kernel(const float* __restrict__ K, const float* __restrict__ V,
                            bf16_t* __restrict__ Kb, bf16_t* __restrict__ VT)
{
    const int blk = blockIdx.x;
    // --- K convert: 16 elts/thread ---
    {
        const size_t base = (size_t)blk * 4096 + (size_t)threadIdx.x * 16;
        fx4 a0 = *(const fx4*)(K + base);
        fx4 a1 = *(const fx4*)(K + base + 4);
        fx4 a2 = *(const fx4*)(K + base + 8);
        fx4 a3 = *(const fx4*)(K + base + 12);
        bf16x8 f0, f1;
        f0[0]=(bf16_t)a0[0]; f0[1]=(bf16_t)a0[1]; f0[2]=(bf16_t)a0[2]; f0[3]=(bf16_t)a0[3];
        f0[4]=(bf16_t)a1[0]; f0[5]=(bf16_t)a1[1]; f0[6]=(bf16_t)a1[2]; f0[7]=(bf16_t)a1[3];
        f1[0]=(bf16_t)a2[0]; f1[1]=(bf16_t)a2[1]; f1[2]=(bf16_t)a2[2]; f1[3]=(bf16_t)a2[3];
        f1[4]=(bf16_t)a3[0]; f1[5]=(bf16_t)a3[1]; f1[6]=(bf16_t)a3[2]; f1[7]=(bf16_t)a3[3];
        *(bf16x8*)(Kb + base)     = f0;
        *(bf16x8*)(Kb + base + 8) = f1;
    }
    // --- V transpose 64x64 tile (s0: seq, c0: channel) ---
    __shared__ __align__(16) bf16_t T[64 * 72];
    const int s0 = (blk & 31) * 64;
    const int c0 = (blk >> 5) * 64;
    const int tx = threadIdx.x & 15, ty = threadIdx.x >> 4;
    fx4 a0 = *(const fx4*)(V + (size_t)(s0 + ty * 4 + 0) * 1024 + c0 + tx * 4);
    fx4 a1 = *(const fx4*)(V + (size_t)(s0 + ty * 4 + 1) * 1024 + c0 + tx * 4);
    fx4 a2 = *(const fx4*)(V + (size_t)(s0 + ty * 4 + 2) * 1024 + c0 + tx * 4);
    fx4 a3 = *(const fx4*)(V + (size_t)(s0 + ty * 4 + 3) * 1024 + c0 + tx * 4);
#pragma unroll
    for (int j = 0; j < 4; ++j) {
        bf16x4 f = { (bf16_t)a0[j], (bf16_t)a1[j], (bf16_t)a2[j], (bf16_t)a3[j] };
        *(bf16x4*)&T[(tx * 4 + j) * 72 + ty * 4] = f;
    }
    __syncthreads();
    const int c = threadIdx.x >> 2, part = threadIdx.x & 3;
    bf16x8 x0 = *(const bf16x8*)&T[c * 72 + part * 16];
    bf16x8 x1 = *(const bf16x8*)&T[c * 72 + part * 16 + 8];
    bf16_t* dst = VT + (size_t)(c0 + c) * 2048 + s0 + part * 16;
    *(bf16x8*)(dst)     = x0;
    *(bf16x8*)(dst + 8) = x1;
}

// ------------------------------- main kernel -------------------------------
__launch_bounds__(256, 1)
__global__ void bsfa_kernel(const float* __restrict__ Q,
                            const bf16_t* __restrict__ Kb,
                            const bf16_t* __restrict__ VT,
                            float* __restrict__ O)
{
    const int blk  = blockIdx.x;            // 256 blocks = 1 per CU
    const int kvh  = blk & 7;               // XCD-pinned kv head
    const int hsub = (blk >> 3) & 3;
    const int x    = blk >> 5;              // 0..7
    const int h    = kvh * 4 + hsub;
    const int tid  = threadIdx.x;           // 0..255
    const int w    = tid >> 6;              // wave 0..3
    const int lane = tid & 63;
    const int l15  = lane & 15;
    const int quad = lane >> 4;
    const bool hi32 = (lane >= 32);

    // balanced qb assignment: per-block wave-tile sum is ~constant (~52)
    const int qb   = (w == 0) ? x : (w == 1) ? (15 - x) : (w == 2) ? (16 + x) : (31 - x);
    const int qA   = x, qB = 15 - x, qC = 16 + x, qD = 31 - x;   // sorted
    const int qmax = qD;

    __shared__ __align__(16) bf16_t Ks[2][64 * 128];   // double-buffered K tile
    __shared__ __align__(16) bf16_t Vs[2][128 * 64];   // double-buffered V^T tile

    const bf16_t* kg = Kb + (size_t)kvh * 128;              // K row stride 1024
    const bf16_t* vg = VT + ((size_t)kvh * 128) * 2048;     // V^T row stride 2048

    // ---- Q fragments (B operand of S^T = K*Q^T), scale*log2e folded in ----
    const int row0 = qb * 64;
    bf16x8 qf[4][4];
#pragma unroll
    for (int qt = 0; qt < 4; ++qt) {
        const float* qp = Q + (size_t)(row0 + qt * 16 + l15) * 4096 + h * 128;
#pragma unroll
        for (int kc = 0; kc < 4; ++kc) {
            fx4 a = *(const fx4*)(qp + kc * 32 + quad * 8);
            fx4 b = *(const fx4*)(qp + kc * 32 + quad * 8 + 4);
            bf16x8 f;
            f[0] = (bf16_t)(a[0] * SL2E_F); f[1] = (bf16_t)(a[1] * SL2E_F);
            f[2] = (bf16_t)(a[2] * SL2E_F); f[3] = (bf16_t)(a[3] * SL2E_F);
            f[4] = (bf16_t)(b[0] * SL2E_F); f[5] = (bf16_t)(b[1] * SL2E_F);
            f[6] = (bf16_t)(b[2] * SL2E_F); f[7] = (bf16_t)(b[3] * SL2E_F);
            qf[qt][kc] = f;
        }
    }

    bf16x8 ones;
#pragma unroll
    for (int i = 0; i < 8; ++i) ones[i] = (bf16_t)1.0f;

    fx4 oacc[8][4];
    fx4 lacc[4];
    const fx4 zero4 = {0.0f, 0.0f, 0.0f, 0.0f};
#pragma unroll
    for (int dt = 0; dt < 8; ++dt)
#pragma unroll
        for (int qt = 0; qt < 4; ++qt) oacc[dt][qt] = zero4;
#pragma unroll
    for (int qt = 0; qt < 4; ++qt) lacc[qt] = zero4;

    // ---- DMA staging: all 256 threads, 4 chunks each per array ----
    auto stage = [&](int kb, int bi) {
        const bf16_t* kt_g = kg + ((size_t)kb << 16);   // kb*64*1024
        const bf16_t* vt_g = vg + ((size_t)kb << 6);    // kb*64
        bf16_t* kd = &Ks[bi][0];
        bf16_t* vd = &Vs[bi][0];
#pragma unroll
        for (int i = 0; i < 4; ++i) {
            const int chunk = i * 256 + tid;            // 16B chunk index, 0..1023
            const int krow  = chunk >> 4;
            const int kc    = (chunk & 15) ^ (krow & 15);   // XOR swizzle
            load_lds16(kt_g + (size_t)krow * 1024 + kc * 8, kd + (size_t)chunk * 8);
            const int vrow  = chunk >> 3;
            const int vc    = (chunk & 7) ^ (vrow & 7);
            load_lds16(vt_g + (size_t)vrow * 2048 + vc * 8, vd + (size_t)chunk * 8);
        }
    };

    // kb=0 is active for every block (wave qb=x has x-0 < 16)
    stage(0, 0);
    __syncthreads();                 // prologue drain only

    int kb = 0, cur = 0;
    while (kb >= 0) {
        // next active tile (uniform scalar scan)
        int nkb = -1;
        for (int t = kb + 1; t <= qmax; ++t) {
            const bool st  = ((t + h + 1) & 7) == 0;
            const bool any = st ? true
                : ((t <= qA) ||
                   (t <= qB && qB - t < 16) ||
                   (t <= qC && qC - t < 16) ||
                   (t <= qD && qD - t < 16));
            if (any) { nkb = t; break; }
        }
        if (nkb >= 0) stage(nkb, cur ^ 1);   // prefetch into other buffer

        const bool act = (kb <= qb) && ((qb - kb < 16) || (((kb + h + 1) & 7) == 0));
        if (act) {
            const bf16_t* kd = &Ks[cur][0];
            const bf16_t* vd = &Vs[cur][0];

            // ---- S^T = K * Q^T ----
            fx4 sacc[4][4];
#pragma unroll
            for (int kt = 0; kt < 4; ++kt)
#pragma unroll
                for (int qt = 0; qt < 4; ++qt) sacc[kt][qt] = zero4;
#pragma unroll
            for (int kc = 0; kc < 4; ++kc)
#pragma unroll
                for (int kt = 0; kt < 4; ++kt) {
                    bf16x8 kf = *(const bf16x8*)&kd[(kt * 16 + l15) * 128 + ((kc * 4 + quad) ^ l15) * 8];
#pragma unroll
                    for (int qt = 0; qt < 4; ++qt)
                        sacc[kt][qt] = __builtin_amdgcn_mfma_f32_16x16x32_bf16(
                            kf, qf[qt][kc], sacc[kt][qt], 0, 0, 0);
                }

            // ---- causal mask on diagonal block ----
            if (kb == qb) {
#pragma unroll
                for (int kt = 0; kt < 4; ++kt)
#pragma unroll
                    for (int qt = 0; qt < 4; ++qt)
#pragma unroll
                        for (int r = 0; r < 4; ++r) {
                            const int k_in = kt * 16 + quad * 4 + r;
                            const int q_in = qt * 16 + l15;
                            if (q_in < k_in) sacc[kt][qt][r] = -1e30f;
                        }
            }

            // ---- no-max softmax: p = 2^s ----
#pragma unroll
            for (int kt = 0; kt < 4; ++kt)
#pragma unroll
                for (int qt = 0; qt < 4; ++qt)
#pragma unroll
                    for (int r = 0; r < 4; ++r)
                        sacc[kt][qt][r] = exp2f(sacc[kt][qt][r]);

            // ---- in-register C->B transform (replaces P LDS overlay) ----
            // target pf[qt][kcg] word m (k = kcg*32 + quad*8 + 2m+{0,1}, col l15):
            //   src kt' = 2kcg + (quad>>1)  -> hi32 select
            //   src quad' = 2(quad&1) + (m>>1) -> quad_gather P0/P1
            //   src word = m&1 (cvt_pk pairs (r0,r1),(r2,r3))
            bf16x8 pf[4][2];
#pragma unroll
            for (int qt = 0; qt < 4; ++qt)
#pragma unroll
                for (int kcg = 0; kcg < 2; ++kcg) {
                    const unsigned a00 = cvt_pk_bf16(sacc[2*kcg  ][qt][0], sacc[2*kcg  ][qt][1]);
                    const unsigned a01 = cvt_pk_bf16(sacc[2*kcg  ][qt][2], sacc[2*kcg  ][qt][3]);
                    const unsigned a10 = cvt_pk_bf16(sacc[2*kcg+1][qt][0], sacc[2*kcg+1][qt][1]);
                    const unsigned a11 = cvt_pk_bf16(sacc[2*kcg+1][qt][2], sacc[2*kcg+1][qt][3]);
                    const u32x2 g00 = quad_gather(a00);
                    const u32x2 g01 = quad_gather(a01);
                    const u32x2 g10 = quad_gather(a10);
                    const u32x2 g11 = quad_gather(a11);
                    u32x4 pw;
                    pw[0] = hi32 ? g10[0] : g00[0];
                    pw[1] = hi32 ? g11[0] : g01[0];
                    pw[2] = hi32 ? g10[1] : g00[1];
                    pw[3] = hi32 ? g11[1] : g01[1];
                    pf[qt][kcg] = __builtin_bit_cast(bf16x8, pw);
                }

            // ---- O^T += V^T * P^T ; l += ones * P^T ----
#pragma unroll
            for (int kcg = 0; kcg < 2; ++kcg) {
#pragma unroll
                for (int dt = 0; dt < 8; ++dt) {
                    bf16x8 vf = *(const bf16x8*)&vd[(dt * 16 + l15) * 64 + ((kcg * 4 + quad) ^ (l15 & 7)) * 8];
#pragma unroll
                    for (int qt = 0; qt < 4; ++qt)
                        oacc[dt][qt] = __builtin_amdgcn_mfma_f32_16x16x32_bf16(
                            vf, pf[qt][kcg], oacc[dt][qt], 0, 0, 0);
                }
#pragma unroll
                for (int qt = 0; qt < 4; ++qt)
                    lacc[qt] = __builtin_amdgcn_mfma_f32_16x16x32_bf16(
                        ones, pf[qt][kcg], lacc[qt], 0, 0, 0);
            }
        }

        __syncthreads();   // single barrier: drains next-tile DMA (had full
                           // compute phase to land) + releases buf[cur]
        kb = nkb; cur ^= 1;
    }

    // ---- epilogue: each wave stores its own 64 rows ----
#pragma unroll
    for (int qt = 0; qt < 4; ++qt) {
        const float inv = 1.0f / lacc[qt][0];   // all rows of lacc identical
#pragma unroll
        for (int dt = 0; dt < 8; ++dt) {
            fx4 o = oacc[dt][qt] * inv;
            *(fx4*)(O + (size_t)(row0 + qt * 16 + l15) * 4096 + h * 128 + dt * 16 + quad * 4) = o;
        }
    }
}

extern "C" void kernel_launch(void* const* d_in, const int* in_sizes, int n_in,
                              void* d_out, int out_size, void* d_ws, size_t ws_size,
                              hipStream_t stream) {
    (void)in_sizes; (void)n_in; (void)ws_size; (void)out_size;
    const float* q = (const float*)d_in[0];
    const float* k = (const float*)d_in[1];
    const float* v = (const float*)d_in[2];
    float* o = (float*)d_out;

    bf16_t* Kb = (bf16_t*)d_ws;                       // [2048][1024] bf16 = 4 MB
    bf16_t* VT = Kb + (size_t)2048 * 1024;            // [1024][2048] bf16 = 4 MB

    prep_kernel<<<dim3(512), dim3(256), 0, stream>>>(k, v, Kb, VT);
    bsfa_kernel<<<dim3(256), dim3(256), 0, stream>>>(q, Kb, VT, o);
}

// Round 3
// 164.606 us; speedup vs baseline: 1.1971x; 1.1971x over previous
//
#include <hip/hip_runtime.h>

// BlockSparseFlashAttention — Phi-3-small blocksparse prefill, MI355X (gfx950)
// S=2048, H=32, HKV=8 (GQA x4), D=128, BLK=64, LOCAL=16, VERT=8, HEAD_SLIDE=1
//
// R9. R8 (direct-global frags, no LDS) failed correctness for reasons not
// identifiable by inspection (suspect: regalloc at ~450 VGPR or exp2 builtin).
// Revert to VERIFIED components only:
//  - R6 (passed, 63.7us): 1024 blocks = (kvh, hsub, qb), 2 waves SAME qb
//    (rh row-split), XOR-swizzled K/V LDS staging, exp2f no-max softmax,
//    l-via-ones-MFMA, XCD pin kvh=blk&7, heavy-qb-first.
//  - R7 (passed correctness): double-buffered staging with ONE barrier per
//    tile (stage(t+1) -> compute(t) -> syncthreads), in-register P transform
//    (cvt_pk_bf16 + permlane32/16_swap) replacing the P LDS overlay.
// R7's perf defect was union-coupling of 4 different-qb waves; with same-qb
// waves the active set is identical for both waves -> no idle iterations.
// New logic this round (only): closed-form active-kb enumerator
// (strided kb = -(h+1) mod 8, step 8, while kb <= qb-16; then local
// max(0,qb-15)..qb) -- block-uniform, replaces the per-iter scan.

typedef __bf16 bf16_t;
typedef __bf16 bf16x4 __attribute__((ext_vector_type(4)));
typedef __bf16 bf16x8 __attribute__((ext_vector_type(8)));
typedef float  fx4    __attribute__((ext_vector_type(4)));
typedef unsigned u32x2 __attribute__((ext_vector_type(2)));
typedef unsigned u32x4 __attribute__((ext_vector_type(4)));

#define SL2E_F 0.1275240614354876f   // (1/sqrt(128)) * log2(e)

__device__ inline void load_lds16(const bf16_t* g, bf16_t* l) {
    __builtin_amdgcn_global_load_lds(
        (const __attribute__((address_space(1))) void*)g,
        (__attribute__((address_space(3))) void*)l, 16, 0, 0);
}

__device__ inline unsigned cvt_pk_bf16(float lo, float hi) {
    unsigned r;
    asm("v_cvt_pk_bf16_f32 %0, %1, %2" : "=v"(r) : "v"(lo), "v"(hi));
    return r;
}

// Quad-gathers of A across the 4 quads (16-lane groups):
//   ret[0] lane(q,c) = A[ (q&1 ? 2 : 0)*16 + c ]
//   ret[1] lane(q,c) = A[ (q&1 ? 3 : 1)*16 + c ]
__device__ inline u32x2 quad_gather(unsigned A) {
    u32x2 bc = __builtin_amdgcn_permlane32_swap(A, A, false, false);
    return __builtin_amdgcn_permlane16_swap(bc[0], bc[1], false, false);
}

// ---- fused pre-pass: K fp32->bf16 (same layout) + V -> V^T bf16 ----------
__global__ void prep_kernel(const float* __restrict__ K, const float* __restrict__ V,
                            bf16_t* __restrict__ Kb, bf16_t* __restrict__ VT)
{
    const int blk = blockIdx.x;
    // --- K convert: 16 elts/thread ---
    {
        const size_t base = (size_t)blk * 4096 + (size_t)threadIdx.x * 16;
        fx4 a0 = *(const fx4*)(K + base);
        fx4 a1 = *(const fx4*)(K + base + 4);
        fx4 a2 = *(const fx4*)(K + base + 8);
        fx4 a3 = *(const fx4*)(K + base + 12);
        bf16x8 f0, f1;
        f0[0]=(bf16_t)a0[0]; f0[1]=(bf16_t)a0[1]; f0[2]=(bf16_t)a0[2]; f0[3]=(bf16_t)a0[3];
        f0[4]=(bf16_t)a1[0]; f0[5]=(bf16_t)a1[1]; f0[6]=(bf16_t)a1[2]; f0[7]=(bf16_t)a1[3];
        f1[0]=(bf16_t)a2[0]; f1[1]=(bf16_t)a2[1]; f1[2]=(bf16_t)a2[2]; f1[3]=(bf16_t)a2[3];
        f1[4]=(bf16_t)a3[0]; f1[5]=(bf16_t)a3[1]; f1[6]=(bf16_t)a3[2]; f1[7]=(bf16_t)a3[3];
        *(bf16x8*)(Kb + base)     = f0;
        *(bf16x8*)(Kb + base + 8) = f1;
    }
    // --- V transpose 64x64 tile (s0: seq, c0: channel) ---
    __shared__ __align__(16) bf16_t T[64 * 72];
    const int s0 = (blk & 31) * 64;
    const int c0 = (blk >> 5) * 64;
    const int tx = threadIdx.x & 15, ty = threadIdx.x >> 4;
    fx4 a0 = *(const fx4*)(V + (size_t)(s0 + ty * 4 + 0) * 1024 + c0 + tx * 4);
    fx4 a1 = *(const fx4*)(V + (size_t)(s0 + ty * 4 + 1) * 1024 + c0 + tx * 4);
    fx4 a2 = *(const fx4*)(V + (size_t)(s0 + ty * 4 + 2) * 1024 + c0 + tx * 4);
    fx4 a3 = *(const fx4*)(V + (size_t)(s0 + ty * 4 + 3) * 1024 + c0 + tx * 4);
#pragma unroll
    for (int j = 0; j < 4; ++j) {
        bf16x4 f = { (bf16_t)a0[j], (bf16_t)a1[j], (bf16_t)a2[j], (bf16_t)a3[j] };
        *(bf16x4*)&T[(tx * 4 + j) * 72 + ty * 4] = f;
    }
    __syncthreads();
    const int c = threadIdx.x >> 2, part = threadIdx.x & 3;
    bf16x8 x0 = *(const bf16x8*)&T[c * 72 + part * 16];
    bf16x8 x1 = *(const bf16x8*)&T[c * 72 + part * 16 + 8];
    bf16_t* dst = VT + (size_t)(c0 + c) * 2048 + s0 + part * 16;
    *(bf16x8*)(dst)     = x0;
    *(bf16x8*)(dst + 8) = x1;
}

// ------------------------------- main kernel -------------------------------
__launch_bounds__(128, 1)
__global__ void bsfa_kernel(const float* __restrict__ Q,
                            const bf16_t* __restrict__ Kb,
                            const bf16_t* __restrict__ VT,
                            float* __restrict__ O)
{
    const int blk  = blockIdx.x;                // 1024 blocks
    const int kvh  = blk & 7;                   // XCD-pinned kv head
    const int h    = kvh * 4 + ((blk >> 3) & 3);
    const int qb   = 31 - (blk >> 5);           // heavy query blocks first
    const int tid  = threadIdx.x;               // 0..127
    const int rh   = tid >> 6;                  // wave = row half (32 rows)
    const int lane = tid & 63;
    const int l15  = lane & 15;
    const int quad = lane >> 4;
    const bool hi32 = (lane >= 32);

    __shared__ __align__(16) bf16_t Ks[2][64 * 128];   // dbuf K tile   (32 KB)
    __shared__ __align__(16) bf16_t Vs[2][128 * 64];   // dbuf V^T tile (32 KB)

    const int row0 = qb * 64 + rh * 32;

    const bf16_t* kg = Kb + (size_t)kvh * 128;              // K row stride 1024
    const bf16_t* vg = VT + ((size_t)kvh * 128) * 2048;     // V^T row stride 2048

    // ---- Q fragments (B operand of S^T = K*Q^T), scale*log2e folded in ----
    bf16x8 qf[2][4];
#pragma unroll
    for (int qt = 0; qt < 2; ++qt) {
        const float* qp = Q + (size_t)(row0 + qt * 16 + l15) * 4096 + h * 128;
#pragma unroll
        for (int kc = 0; kc < 4; ++kc) {
            fx4 a = *(const fx4*)(qp + kc * 32 + quad * 8);
            fx4 b = *(const fx4*)(qp + kc * 32 + quad * 8 + 4);
            bf16x8 f;
            f[0] = (bf16_t)(a[0] * SL2E_F); f[1] = (bf16_t)(a[1] * SL2E_F);
            f[2] = (bf16_t)(a[2] * SL2E_F); f[3] = (bf16_t)(a[3] * SL2E_F);
            f[4] = (bf16_t)(b[0] * SL2E_F); f[5] = (bf16_t)(b[1] * SL2E_F);
            f[6] = (bf16_t)(b[2] * SL2E_F); f[7] = (bf16_t)(b[3] * SL2E_F);
            qf[qt][kc] = f;
        }
    }

    bf16x8 ones;
#pragma unroll
    for (int i = 0; i < 8; ++i) ones[i] = (bf16_t)1.0f;

    fx4 oacc[8][2];
    fx4 lacc[2];
    const fx4 zero4 = {0.0f, 0.0f, 0.0f, 0.0f};
#pragma unroll
    for (int dt = 0; dt < 8; ++dt)
#pragma unroll
        for (int qt = 0; qt < 2; ++qt) oacc[dt][qt] = zero4;
    lacc[0] = zero4; lacc[1] = zero4;

    // ---- staging (R6-verified swizzle, dbuf-indexed) ----
    auto stage = [&](int kb, int bi) {
        const bf16_t* kt_g = kg + ((size_t)kb << 16);   // kb*64*1024
        const bf16_t* vt_g = vg + ((size_t)kb << 6);    // kb*64
        bf16_t* kd = &Ks[bi][0];
        bf16_t* vd = &Vs[bi][0];
#pragma unroll
        for (int i = 0; i < 8; ++i) {
            const int chunk = i * 128 + tid;            // 16B chunk index
            const int krow = chunk >> 4;
            const int kc   = (chunk & 15) ^ (krow & 15);   // XOR swizzle
            load_lds16(kt_g + (size_t)krow * 1024 + kc * 8, kd + (size_t)chunk * 8);
            const int vrow = chunk >> 3;
            const int vc   = (chunk & 7) ^ (vrow & 7);
            load_lds16(vt_g + (size_t)vrow * 2048 + vc * 8, vd + (size_t)chunk * 8);
        }
    };

    // ---- closed-form active-kb enumerator (block-uniform) ----
    // strided phase: kb = kb0s, kb0s+8, ... while kb <= qb-16
    // local phase:   kb = loc0 .. qb   where loc0 = max(0, qb-15)
    const int loc0 = (qb > 15) ? (qb - 15) : 0;
    const int kb0s = (8 - ((h + 1) & 7)) & 7;     // smallest kb with (kb+h+1)%8==0
    auto nxt = [&](int kb) -> int {
        if (kb < loc0) { const int t = kb + 8; return (t <= qb - 16) ? t : loc0; }
        return (kb < qb) ? (kb + 1) : -1;
    };

    int kb = (qb - 16 >= kb0s) ? kb0s : loc0;
    stage(kb, 0);
    __syncthreads();                 // prologue drain only

    int cur = 0;
    while (kb >= 0) {
        const int nkb = nxt(kb);
        if (nkb >= 0) stage(nkb, cur ^ 1);   // prefetch next tile (other buf)

        const bf16_t* kd = &Ks[cur][0];
        const bf16_t* vd = &Vs[cur][0];

        // ---- S^T = K * Q^T (K frags from swizzled LDS) ----
        fx4 sacc[4][2];
#pragma unroll
        for (int kt = 0; kt < 4; ++kt)
#pragma unroll
            for (int qt = 0; qt < 2; ++qt) sacc[kt][qt] = zero4;
#pragma unroll
        for (int kc = 0; kc < 4; ++kc)
#pragma unroll
            for (int kt = 0; kt < 4; ++kt) {
                bf16x8 kf = *(const bf16x8*)&kd[(kt * 16 + l15) * 128 + ((kc * 4 + quad) ^ l15) * 8];
#pragma unroll
                for (int qt = 0; qt < 2; ++qt)
                    sacc[kt][qt] = __builtin_amdgcn_mfma_f32_16x16x32_bf16(
                        kf, qf[qt][kc], sacc[kt][qt], 0, 0, 0);
            }

        // ---- causal mask on the diagonal block ----
        if (kb == qb) {
#pragma unroll
            for (int kt = 0; kt < 4; ++kt)
#pragma unroll
                for (int qt = 0; qt < 2; ++qt)
#pragma unroll
                    for (int r = 0; r < 4; ++r) {
                        const int k_in = kt * 16 + quad * 4 + r;
                        const int q_in = rh * 32 + qt * 16 + l15;
                        if (q_in < k_in) sacc[kt][qt][r] = -1e30f;
                    }
        }

        // ---- no-max softmax: p = 2^s ----
#pragma unroll
        for (int kt = 0; kt < 4; ++kt)
#pragma unroll
            for (int qt = 0; qt < 2; ++qt)
#pragma unroll
                for (int r = 0; r < 4; ++r)
                    sacc[kt][qt][r] = exp2f(sacc[kt][qt][r]);

        // ---- in-register C->B transform (R7-verified) ----
        bf16x8 pf[2][2];
#pragma unroll
        for (int qt = 0; qt < 2; ++qt)
#pragma unroll
            for (int kcg = 0; kcg < 2; ++kcg) {
                const unsigned a00 = cvt_pk_bf16(sacc[2*kcg  ][qt][0], sacc[2*kcg  ][qt][1]);
                const unsigned a01 = cvt_pk_bf16(sacc[2*kcg  ][qt][2], sacc[2*kcg  ][qt][3]);
                const unsigned a10 = cvt_pk_bf16(sacc[2*kcg+1][qt][0], sacc[2*kcg+1][qt][1]);
                const unsigned a11 = cvt_pk_bf16(sacc[2*kcg+1][qt][2], sacc[2*kcg+1][qt][3]);
                const u32x2 g00 = quad_gather(a00);
                const u32x2 g01 = quad_gather(a01);
                const u32x2 g10 = quad_gather(a10);
                const u32x2 g11 = quad_gather(a11);
                u32x4 pw;
                pw[0] = hi32 ? g10[0] : g00[0];
                pw[1] = hi32 ? g11[0] : g01[0];
                pw[2] = hi32 ? g10[1] : g00[1];
                pw[3] = hi32 ? g11[1] : g01[1];
                pf[qt][kcg] = __builtin_bit_cast(bf16x8, pw);
            }

        // ---- O^T += V^T * P^T ; l += ones * P^T (V frags from swizzled LDS) ----
#pragma unroll
        for (int kcg = 0; kcg < 2; ++kcg) {
#pragma unroll
            for (int dt = 0; dt < 8; ++dt) {
                bf16x8 vf = *(const bf16x8*)&vd[(dt * 16 + l15) * 64 + ((kcg * 4 + quad) ^ (l15 & 7)) * 8];
#pragma unroll
                for (int qt = 0; qt < 2; ++qt)
                    oacc[dt][qt] = __builtin_amdgcn_mfma_f32_16x16x32_bf16(
                        vf, pf[qt][kcg], oacc[dt][qt], 0, 0, 0);
            }
#pragma unroll
            for (int qt = 0; qt < 2; ++qt)
                lacc[qt] = __builtin_amdgcn_mfma_f32_16x16x32_bf16(
                    ones, pf[qt][kcg], lacc[qt], 0, 0, 0);
        }

        __syncthreads();   // single barrier: drains next-tile DMA (which had
                           // the whole compute phase to land) + releases cur
        kb = nkb; cur ^= 1;
    }

    // ---- epilogue: each wave stores its own 32 rows ----
#pragma unroll
    for (int qt = 0; qt < 2; ++qt) {
        const float inv = 1.0f / lacc[qt][0];   // all rows of lacc identical
#pragma unroll
        for (int dt = 0; dt < 8; ++dt) {
            fx4 o = oacc[dt][qt] * inv;
            *(fx4*)(O + (size_t)(row0 + qt * 16 + l15) * 4096 + h * 128 + dt * 16 + quad * 4) = o;
        }
    }
}

extern "C" void kernel_launch(void* const* d_in, const int* in_sizes, int n_in,
                              void* d_out, int out_size, void* d_ws, size_t ws_size,
                              hipStream_t stream) {
    (void)in_sizes; (void)n_in; (void)ws_size; (void)out_size;
    const float* q = (const float*)d_in[0];
    const float* k = (const float*)d_in[1];
    const float* v = (const float*)d_in[2];
    float* o = (float*)d_out;

    bf16_t* Kb = (bf16_t*)d_ws;                       // [2048][1024] bf16 = 4 MB
    bf16_t* VT = Kb + (size_t)2048 * 1024;            // [1024][2048] bf16 = 4 MB

    prep_kernel<<<dim3(512), dim3(256), 0, stream>>>(k, v, Kb, VT);
    bsfa_kernel<<<dim3(1024), dim3(128), 0, stream>>>(q, Kb, VT, o);
}

// Round 4
// 162.187 us; speedup vs baseline: 1.2150x; 1.0149x over previous
//
#include <hip/hip_runtime.h>

// BlockSparseFlashAttention — Phi-3-small blocksparse prefill, MI355X (gfx950)
// S=2048, H=32, HKV=8 (GQA x4), D=128, BLK=64, LOCAL=16, VERT=8, HEAD_SLIDE=1
//
// R10. Evidence across R6(63us)/R7(118)/R9(88): perf tracks co-resident
// blocks/CU (4 -> best), not barrier count; per-tile critical path is
// latency-dominated. So: restore 4-5 blocks/CU AND keep the 1-barrier dbuf
// pipeline by cutting LDS to a K-only 32KB double buffer.
//  - V^T fragments read DIRECTLY from L2 (kvh slice = 1 MB, XCD-pinned,
//    L2-resident per FETCH_SIZE). Addressing derived element-identical to
//    the verified staged path (XOR swizzles cancel). V loads issued in two
//    8-load groups (kcg0 before QK, kcg1 after QK) so L2 latency hides under
//    QK/softmax and stays vmcnt-counted across no barrier. VGPR peak <=256.
//  - K path UNCHANGED (verified DMA+swizzle), now dbuf: stage(next) ->
//    compute(cur) -> one __syncthreads per tile (R9-verified structure).
//  - verified R6 mapping kept: 1024 blocks=(kvh,hsub,qb), 2 waves same qb
//    (rh split), exp2f no-max softmax, l-via-ones-MFMA, heavy-qb-first.
//  - R7/R9-verified in-register P transform (cvt_pk + permlane).
//  - R9-verified closed-form active-kb enumerator.

typedef __bf16 bf16_t;
typedef __bf16 bf16x4 __attribute__((ext_vector_type(4)));
typedef __bf16 bf16x8 __attribute__((ext_vector_type(8)));
typedef float  fx4    __attribute__((ext_vector_type(4)));
typedef unsigned u32x2 __attribute__((ext_vector_type(2)));
typedef unsigned u32x4 __attribute__((ext_vector_type(4)));

#define SL2E_F 0.1275240614354876f   // (1/sqrt(128)) * log2(e)

__device__ inline void load_lds16(const bf16_t* g, bf16_t* l) {
    __builtin_amdgcn_global_load_lds(
        (const __attribute__((address_space(1))) void*)g,
        (__attribute__((address_space(3))) void*)l, 16, 0, 0);
}

__device__ inline unsigned cvt_pk_bf16(float lo, float hi) {
    unsigned r;
    asm("v_cvt_pk_bf16_f32 %0, %1, %2" : "=v"(r) : "v"(lo), "v"(hi));
    return r;
}

// Quad-gathers of A across the 4 quads (16-lane groups):
//   ret[0] lane(q,c) = A[ (q&1 ? 2 : 0)*16 + c ]
//   ret[1] lane(q,c) = A[ (q&1 ? 3 : 1)*16 + c ]
__device__ inline u32x2 quad_gather(unsigned A) {
    u32x2 bc = __builtin_amdgcn_permlane32_swap(A, A, false, false);
    return __builtin_amdgcn_permlane16_swap(bc[0], bc[1], false, false);
}

// ---- fused pre-pass: K fp32->bf16 (same layout) + V -> V^T bf16 ----------
__global__ void prep_kernel(const float* __restrict__ K, const float* __restrict__ V,
                            bf16_t* __restrict__ Kb, bf16_t* __restrict__ VT)
{
    const int blk = blockIdx.x;
    // --- K convert: 16 elts/thread ---
    {
        const size_t base = (size_t)blk * 4096 + (size_t)threadIdx.x * 16;
        fx4 a0 = *(const fx4*)(K + base);
        fx4 a1 = *(const fx4*)(K + base + 4);
        fx4 a2 = *(const fx4*)(K + base + 8);
        fx4 a3 = *(const fx4*)(K + base + 12);
        bf16x8 f0, f1;
        f0[0]=(bf16_t)a0[0]; f0[1]=(bf16_t)a0[1]; f0[2]=(bf16_t)a0[2]; f0[3]=(bf16_t)a0[3];
        f0[4]=(bf16_t)a1[0]; f0[5]=(bf16_t)a1[1]; f0[6]=(bf16_t)a1[2]; f0[7]=(bf16_t)a1[3];
        f1[0]=(bf16_t)a2[0]; f1[1]=(bf16_t)a2[1]; f1[2]=(bf16_t)a2[2]; f1[3]=(bf16_t)a2[3];
        f1[4]=(bf16_t)a3[0]; f1[5]=(bf16_t)a3[1]; f1[6]=(bf16_t)a3[2]; f1[7]=(bf16_t)a3[3];
        *(bf16x8*)(Kb + base)     = f0;
        *(bf16x8*)(Kb + base + 8) = f1;
    }
    // --- V transpose 64x64 tile (s0: seq, c0: channel) ---
    __shared__ __align__(16) bf16_t T[64 * 72];
    const int s0 = (blk & 31) * 64;
    const int c0 = (blk >> 5) * 64;
    const int tx = threadIdx.x & 15, ty = threadIdx.x >> 4;
    fx4 a0 = *(const fx4*)(V + (size_t)(s0 + ty * 4 + 0) * 1024 + c0 + tx * 4);
    fx4 a1 = *(const fx4*)(V + (size_t)(s0 + ty * 4 + 1) * 1024 + c0 + tx * 4);
    fx4 a2 = *(const fx4*)(V + (size_t)(s0 + ty * 4 + 2) * 1024 + c0 + tx * 4);
    fx4 a3 = *(const fx4*)(V + (size_t)(s0 + ty * 4 + 3) * 1024 + c0 + tx * 4);
#pragma unroll
    for (int j = 0; j < 4; ++j) {
        bf16x4 f = { (bf16_t)a0[j], (bf16_t)a1[j], (bf16_t)a2[j], (bf16_t)a3[j] };
        *(bf16x4*)&T[(tx * 4 + j) * 72 + ty * 4] = f;
    }
    __syncthreads();
    const int c = threadIdx.x >> 2, part = threadIdx.x & 3;
    bf16x8 x0 = *(const bf16x8*)&T[c * 72 + part * 16];
    bf16x8 x1 = *(const bf16x8*)&T[c * 72 + part * 16 + 8];
    bf16_t* dst = VT + (size_t)(c0 + c) * 2048 + s0 + part * 16;
    *(bf16x8*)(dst)     = x0;
    *(bf16x8*)(dst + 8) = x1;
}

// ------------------------------- main kernel -------------------------------
__launch_bounds__(128, 2)
__global__ void bsfa_kernel(const float* __restrict__ Q,
                            const bf16_t* __restrict__ Kb,
                            const bf16_t* __restrict__ VT,
                            float* __restrict__ O)
{
    const int blk  = blockIdx.x;                // 1024 blocks
    const int kvh  = blk & 7;                   // XCD-pinned kv head
    const int h    = kvh * 4 + ((blk >> 3) & 3);
    const int qb   = 31 - (blk >> 5);           // heavy query blocks first
    const int tid  = threadIdx.x;               // 0..127
    const int rh   = tid >> 6;                  // wave = row half (32 rows)
    const int lane = tid & 63;
    const int l15  = lane & 15;
    const int quad = lane >> 4;
    const bool hi32 = (lane >= 32);

    __shared__ __align__(16) bf16_t Ks[2][64 * 128];   // dbuf K tile (32 KB total)

    const int row0 = qb * 64 + rh * 32;

    const bf16_t* kg = Kb + (size_t)kvh * 128;              // K row stride 1024
    // per-lane V^T fragment base (direct L2 reads; XOR-cancel-verified layout)
    const bf16_t* vbase = VT + ((size_t)kvh * 128 + l15) * 2048 + quad * 8;

    // ---- Q fragments (B operand of S^T = K*Q^T), scale*log2e folded in ----
    bf16x8 qf[2][4];
#pragma unroll
    for (int qt = 0; qt < 2; ++qt) {
        const float* qp = Q + (size_t)(row0 + qt * 16 + l15) * 4096 + h * 128;
#pragma unroll
        for (int kc = 0; kc < 4; ++kc) {
            fx4 a = *(const fx4*)(qp + kc * 32 + quad * 8);
            fx4 b = *(const fx4*)(qp + kc * 32 + quad * 8 + 4);
            bf16x8 f;
            f[0] = (bf16_t)(a[0] * SL2E_F); f[1] = (bf16_t)(a[1] * SL2E_F);
            f[2] = (bf16_t)(a[2] * SL2E_F); f[3] = (bf16_t)(a[3] * SL2E_F);
            f[4] = (bf16_t)(b[0] * SL2E_F); f[5] = (bf16_t)(b[1] * SL2E_F);
            f[6] = (bf16_t)(b[2] * SL2E_F); f[7] = (bf16_t)(b[3] * SL2E_F);
            qf[qt][kc] = f;
        }
    }

    bf16x8 ones;
#pragma unroll
    for (int i = 0; i < 8; ++i) ones[i] = (bf16_t)1.0f;

    fx4 oacc[8][2];
    fx4 lacc[2];
    const fx4 zero4 = {0.0f, 0.0f, 0.0f, 0.0f};
#pragma unroll
    for (int dt = 0; dt < 8; ++dt)
#pragma unroll
        for (int qt = 0; qt < 2; ++qt) oacc[dt][qt] = zero4;
    lacc[0] = zero4; lacc[1] = zero4;

    // ---- K staging (R6-verified swizzle, dbuf-indexed; K only) ----
    auto stage = [&](int kb, int bi) {
        const bf16_t* kt_g = kg + ((size_t)kb << 16);   // kb*64*1024
        bf16_t* kd = &Ks[bi][0];
#pragma unroll
        for (int i = 0; i < 8; ++i) {
            const int chunk = i * 128 + tid;            // 16B chunk index, 0..1023
            const int krow = chunk >> 4;
            const int kc   = (chunk & 15) ^ (krow & 15);   // XOR swizzle
            load_lds16(kt_g + (size_t)krow * 1024 + kc * 8, kd + (size_t)chunk * 8);
        }
    };

    // ---- closed-form active-kb enumerator (R9-verified, block-uniform) ----
    const int loc0 = (qb > 15) ? (qb - 15) : 0;
    const int kb0s = (8 - ((h + 1) & 7)) & 7;     // smallest kb with (kb+h+1)%8==0
    auto nxt = [&](int kb) -> int {
        if (kb < loc0) { const int t = kb + 8; return (t <= qb - 16) ? t : loc0; }
        return (kb < qb) ? (kb + 1) : -1;
    };

    int kb = (qb - 16 >= kb0s) ? kb0s : loc0;
    stage(kb, 0);
    __syncthreads();                 // prologue drain only

    int cur = 0;
    while (kb >= 0) {
        const int nkb = nxt(kb);
        if (nkb >= 0) stage(nkb, cur ^ 1);   // prefetch next K tile (other buf)

        const bf16_t* kd = &Ks[cur][0];
        const bf16_t* vp = vbase + ((size_t)kb << 6);   // kb*64 cols

        // ---- V group 0 (kcg=0): issue before QK, lands under it ----
        bf16x8 vfr0[8];
#pragma unroll
        for (int dt = 0; dt < 8; ++dt)
            vfr0[dt] = *(const bf16x8*)(vp + (size_t)(dt * 16) * 2048);

        // ---- S^T = K * Q^T (K frags from swizzled LDS) ----
        fx4 sacc[4][2];
#pragma unroll
        for (int kt = 0; kt < 4; ++kt)
#pragma unroll
            for (int qt = 0; qt < 2; ++qt) sacc[kt][qt] = zero4;
#pragma unroll
        for (int kc = 0; kc < 4; ++kc)
#pragma unroll
            for (int kt = 0; kt < 4; ++kt) {
                bf16x8 kf = *(const bf16x8*)&kd[(kt * 16 + l15) * 128 + ((kc * 4 + quad) ^ l15) * 8];
#pragma unroll
                for (int qt = 0; qt < 2; ++qt)
                    sacc[kt][qt] = __builtin_amdgcn_mfma_f32_16x16x32_bf16(
                        kf, qf[qt][kc], sacc[kt][qt], 0, 0, 0);
            }

        // ---- V group 1 (kcg=1): issue after QK, lands under softmax ----
        bf16x8 vfr1[8];
#pragma unroll
        for (int dt = 0; dt < 8; ++dt)
            vfr1[dt] = *(const bf16x8*)(vp + (size_t)(dt * 16) * 2048 + 32);

        // ---- causal mask on the diagonal block ----
        if (kb == qb) {
#pragma unroll
            for (int kt = 0; kt < 4; ++kt)
#pragma unroll
                for (int qt = 0; qt < 2; ++qt)
#pragma unroll
                    for (int r = 0; r < 4; ++r) {
                        const int k_in = kt * 16 + quad * 4 + r;
                        const int q_in = rh * 32 + qt * 16 + l15;
                        if (q_in < k_in) sacc[kt][qt][r] = -1e30f;
                    }
        }

        // ---- no-max softmax: p = 2^s ----
#pragma unroll
        for (int kt = 0; kt < 4; ++kt)
#pragma unroll
            for (int qt = 0; qt < 2; ++qt)
#pragma unroll
                for (int r = 0; r < 4; ++r)
                    sacc[kt][qt][r] = exp2f(sacc[kt][qt][r]);

        // ---- in-register C->B transform (R7/R9-verified) ----
        bf16x8 pf[2][2];
#pragma unroll
        for (int qt = 0; qt < 2; ++qt)
#pragma unroll
            for (int kcg = 0; kcg < 2; ++kcg) {
                const unsigned a00 = cvt_pk_bf16(sacc[2*kcg  ][qt][0], sacc[2*kcg  ][qt][1]);
                const unsigned a01 = cvt_pk_bf16(sacc[2*kcg  ][qt][2], sacc[2*kcg  ][qt][3]);
                const unsigned a10 = cvt_pk_bf16(sacc[2*kcg+1][qt][0], sacc[2*kcg+1][qt][1]);
                const unsigned a11 = cvt_pk_bf16(sacc[2*kcg+1][qt][2], sacc[2*kcg+1][qt][3]);
                const u32x2 g00 = quad_gather(a00);
                const u32x2 g01 = quad_gather(a01);
                const u32x2 g10 = quad_gather(a10);
                const u32x2 g11 = quad_gather(a11);
                u32x4 pw;
                pw[0] = hi32 ? g10[0] : g00[0];
                pw[1] = hi32 ? g11[0] : g01[0];
                pw[2] = hi32 ? g10[1] : g00[1];
                pw[3] = hi32 ? g11[1] : g01[1];
                pf[qt][kcg] = __builtin_bit_cast(bf16x8, pw);
            }

        // ---- O^T += V^T * P^T ; l += ones * P^T (V frags from registers) ----
#pragma unroll
        for (int dt = 0; dt < 8; ++dt)
#pragma unroll
            for (int qt = 0; qt < 2; ++qt)
                oacc[dt][qt] = __builtin_amdgcn_mfma_f32_16x16x32_bf16(
                    vfr0[dt], pf[qt][0], oacc[dt][qt], 0, 0, 0);
#pragma unroll
        for (int qt = 0; qt < 2; ++qt)
            lacc[qt] = __builtin_amdgcn_mfma_f32_16x16x32_bf16(
                ones, pf[qt][0], lacc[qt], 0, 0, 0);
#pragma unroll
        for (int dt = 0; dt < 8; ++dt)
#pragma unroll
            for (int qt = 0; qt < 2; ++qt)
                oacc[dt][qt] = __builtin_amdgcn_mfma_f32_16x16x32_bf16(
                    vfr1[dt], pf[qt][1], oacc[dt][qt], 0, 0, 0);
#pragma unroll
        for (int qt = 0; qt < 2; ++qt)
            lacc[qt] = __builtin_amdgcn_mfma_f32_16x16x32_bf16(
                ones, pf[qt][1], lacc[qt], 0, 0, 0);

        __syncthreads();   // single barrier: drains next-tile K DMA (which had
                           // the whole compute phase to land) + releases cur
        kb = nkb; cur ^= 1;
    }

    // ---- epilogue: each wave stores its own 32 rows ----
#pragma unroll
    for (int qt = 0; qt < 2; ++qt) {
        const float inv = 1.0f / lacc[qt][0];   // all rows of lacc identical
#pragma unroll
        for (int dt = 0; dt < 8; ++dt) {
            fx4 o = oacc[dt][qt] * inv;
            *(fx4*)(O + (size_t)(row0 + qt * 16 + l15) * 4096 + h * 128 + dt * 16 + quad * 4) = o;
        }
    }
}

extern "C" void kernel_launch(void* const* d_in, const int* in_sizes, int n_in,
                              void* d_out, int out_size, void* d_ws, size_t ws_size,
                              hipStream_t stream) {
    (void)in_sizes; (void)n_in; (void)ws_size; (void)out_size;
    const float* q = (const float*)d_in[0];
    const float* k = (const float*)d_in[1];
    const float* v = (const float*)d_in[2];
    float* o = (float*)d_out;

    bf16_t* Kb = (bf16_t*)d_ws;                       // [2048][1024] bf16 = 4 MB
    bf16_t* VT = Kb + (size_t)2048 * 1024;            // [1024][2048] bf16 = 4 MB

    prep_kernel<<<dim3(512), dim3(256), 0, stream>>>(k, v, Kb, VT);
    bsfa_kernel<<<dim3(1024), dim3(128), 0, stream>>>(q, Kb, VT, o);
}

// Round 5
// 142.769 us; speedup vs baseline: 1.3802x; 1.1360x over previous
//
#include <hip/hip_runtime.h>

// BlockSparseFlashAttention — Phi-3-small blocksparse prefill, MI355X (gfx950)
// S=2048, H=32, HKV=8 (GQA x4), D=128, BLK=64, LOCAL=16, VERT=8, HEAD_SLIDE=1
//
// R11. Evidence after 7 rounds: R6's exact structure (63.4us) beats every
// restructure (R7 118, R9 88, R10 85); every regression traced to a NEW
// memory datapath (union-coupled staging / register-starved direct-global V).
// So: R6 VERBATIM + exactly one verified delta — the P LDS overlay
// (8 ds_write + lgkmcnt(0) + 4 ds_read + one barrier + ALL 1.26M bank
// conflicts) is replaced by the in-register C->B transform (cvt_pk_bf16 +
// permlane32/16_swap), bit-verified at this qt=2 width in passing R7/R9/R10.
// Barriers 3 -> 2 per tile. V stays in LDS (R6 path; no reg-pressure trap —
// pf is built in place from sacc, +~16 VGPR).
// Falsifiable signature: SQ_LDS_BANK_CONFLICT 1.26M -> ~0.

typedef __bf16 bf16_t;
typedef __bf16 bf16x4 __attribute__((ext_vector_type(4)));
typedef __bf16 bf16x8 __attribute__((ext_vector_type(8)));
typedef float  fx4    __attribute__((ext_vector_type(4)));
typedef unsigned u32x2 __attribute__((ext_vector_type(2)));
typedef unsigned u32x4 __attribute__((ext_vector_type(4)));

#define SL2E_F 0.1275240614354876f   // (1/sqrt(128)) * log2(e)

__device__ inline void load_lds16(const bf16_t* g, bf16_t* l) {
    __builtin_amdgcn_global_load_lds(
        (const __attribute__((address_space(1))) void*)g,
        (__attribute__((address_space(3))) void*)l, 16, 0, 0);
}

__device__ inline unsigned cvt_pk_bf16(float lo, float hi) {
    unsigned r;
    asm("v_cvt_pk_bf16_f32 %0, %1, %2" : "=v"(r) : "v"(lo), "v"(hi));
    return r;
}

// Quad-gathers of A across the 4 quads (16-lane groups):
//   ret[0] lane(q,c) = A[ (q&1 ? 2 : 0)*16 + c ]
//   ret[1] lane(q,c) = A[ (q&1 ? 3 : 1)*16 + c ]
__device__ inline u32x2 quad_gather(unsigned A) {
    u32x2 bc = __builtin_amdgcn_permlane32_swap(A, A, false, false);
    return __builtin_amdgcn_permlane16_swap(bc[0], bc[1], false, false);
}

// ---- fused pre-pass: K fp32->bf16 (same layout) + V -> V^T bf16 ----------
// grid 512 x 256thr. Each WG: 4096 K elts converted + one 64x64 V tile
// transposed into VT [1024][2048].
__global__ void prep_kernel(const float* __restrict__ K, const float* __restrict__ V,
                            bf16_t* __restrict__ Kb, bf16_t* __restrict__ VT)
{
    const int blk = blockIdx.x;
    // --- K convert: 16 elts/thread ---
    {
        const size_t base = (size_t)blk * 4096 + (size_t)threadIdx.x * 16;
        fx4 a0 = *(const fx4*)(K + base);
        fx4 a1 = *(const fx4*)(K + base + 4);
        fx4 a2 = *(const fx4*)(K + base + 8);
        fx4 a3 = *(const fx4*)(K + base + 12);
        bf16x8 f0, f1;
        f0[0]=(bf16_t)a0[0]; f0[1]=(bf16_t)a0[1]; f0[2]=(bf16_t)a0[2]; f0[3]=(bf16_t)a0[3];
        f0[4]=(bf16_t)a1[0]; f0[5]=(bf16_t)a1[1]; f0[6]=(bf16_t)a1[2]; f0[7]=(bf16_t)a1[3];
        f1[0]=(bf16_t)a2[0]; f1[1]=(bf16_t)a2[1]; f1[2]=(bf16_t)a2[2]; f1[3]=(bf16_t)a2[3];
        f1[4]=(bf16_t)a3[0]; f1[5]=(bf16_t)a3[1]; f1[6]=(bf16_t)a3[2]; f1[7]=(bf16_t)a3[3];
        *(bf16x8*)(Kb + base)     = f0;
        *(bf16x8*)(Kb + base + 8) = f1;
    }
    // --- V transpose 64x64 tile (s0: seq, c0: channel) ---
    __shared__ __align__(16) bf16_t T[64 * 72];
    const int s0 = (blk & 31) * 64;
    const int c0 = (blk >> 5) * 64;
    const int tx = threadIdx.x & 15, ty = threadIdx.x >> 4;
    fx4 a0 = *(const fx4*)(V + (size_t)(s0 + ty * 4 + 0) * 1024 + c0 + tx * 4);
    fx4 a1 = *(const fx4*)(V + (size_t)(s0 + ty * 4 + 1) * 1024 + c0 + tx * 4);
    fx4 a2 = *(const fx4*)(V + (size_t)(s0 + ty * 4 + 2) * 1024 + c0 + tx * 4);
    fx4 a3 = *(const fx4*)(V + (size_t)(s0 + ty * 4 + 3) * 1024 + c0 + tx * 4);
#pragma unroll
    for (int j = 0; j < 4; ++j) {
        bf16x4 f = { (bf16_t)a0[j], (bf16_t)a1[j], (bf16_t)a2[j], (bf16_t)a3[j] };
        *(bf16x4*)&T[(tx * 4 + j) * 72 + ty * 4] = f;
    }
    __syncthreads();
    const int c = threadIdx.x >> 2, part = threadIdx.x & 3;
    bf16x8 x0 = *(const bf16x8*)&T[c * 72 + part * 16];
    bf16x8 x1 = *(const bf16x8*)&T[c * 72 + part * 16 + 8];
    bf16_t* dst = VT + (size_t)(c0 + c) * 2048 + s0 + part * 16;
    *(bf16x8*)(dst)     = x0;
    *(bf16x8*)(dst + 8) = x1;
}

// ------------------------------- main kernel -------------------------------
__launch_bounds__(128, 2)
__global__ void bsfa_kernel(const float* __restrict__ Q,
                            const bf16_t* __restrict__ Kb,
                            const bf16_t* __restrict__ VT,
                            float* __restrict__ O)
{
    const int blk  = blockIdx.x;
    const int kvh  = blk & 7;                   // XCD-pinned kv head
    const int h    = kvh * 4 + ((blk >> 3) & 3);
    const int qb   = 31 - (blk >> 5);           // heavy query blocks first
    const int tid  = threadIdx.x;               // 0..127
    const int rh   = tid >> 6;                  // wave = row half (32 rows)
    const int lane = tid & 63;
    const int l15  = lane & 15;
    const int quad = lane >> 4;
    const bool hi32 = (lane >= 32);

    __shared__ __align__(16) bf16_t Ks[64 * 128];   // K tile (16 KB)
    __shared__ __align__(16) bf16_t Vs[128 * 64];   // V^T tile (16 KB)

    const int row0 = qb * 64 + rh * 32;

    const bf16_t* kg = Kb + (size_t)kvh * 128;              // K row stride 1024
    const bf16_t* vg = VT + ((size_t)kvh * 128) * 2048;     // V^T row stride 2048

    // ---- Q fragments (B operand of S^T = K*Q^T), scale*log2e folded in ----
    bf16x8 qf[2][4];
#pragma unroll
    for (int qt = 0; qt < 2; ++qt) {
        const float* qp = Q + (size_t)(row0 + qt * 16 + l15) * 4096 + h * 128;
#pragma unroll
        for (int kc = 0; kc < 4; ++kc) {
            fx4 a = *(const fx4*)(qp + kc * 32 + quad * 8);
            fx4 b = *(const fx4*)(qp + kc * 32 + quad * 8 + 4);
            bf16x8 f;
            f[0] = (bf16_t)(a[0] * SL2E_F); f[1] = (bf16_t)(a[1] * SL2E_F);
            f[2] = (bf16_t)(a[2] * SL2E_F); f[3] = (bf16_t)(a[3] * SL2E_F);
            f[4] = (bf16_t)(b[0] * SL2E_F); f[5] = (bf16_t)(b[1] * SL2E_F);
            f[6] = (bf16_t)(b[2] * SL2E_F); f[7] = (bf16_t)(b[3] * SL2E_F);
            qf[qt][kc] = f;
        }
    }

    // ones fragment: A-operand for the l-via-MFMA trick
    bf16x8 ones;
#pragma unroll
    for (int i = 0; i < 8; ++i) ones[i] = (bf16_t)1.0f;

    fx4 oacc[8][2];
    fx4 lacc[2];
    const fx4 zero4 = {0.0f, 0.0f, 0.0f, 0.0f};
#pragma unroll
    for (int dt = 0; dt < 8; ++dt)
#pragma unroll
        for (int qt = 0; qt < 2; ++qt)
            oacc[dt][qt] = zero4;
    lacc[0] = zero4; lacc[1] = zero4;

    for (int kb = 0; kb <= qb; ++kb) {
        if (!((qb - kb < 16) || (((kb + h + 1) & 7) == 0))) continue;

        // ---- DMA-stage K [64][128] and V^T [128][64] (both waves) ----
        {
            const bf16_t* kt_g = kg + ((size_t)kb << 16);   // kb*64*1024
            const bf16_t* vt_g = vg + ((size_t)kb << 6);    // kb*64
#pragma unroll
            for (int i = 0; i < 8; ++i) {
                const int chunk = i * 128 + tid;            // 16B chunk index
                const int krow = chunk >> 4;
                const int kc   = (chunk & 15) ^ (krow & 15);   // XOR swizzle
                load_lds16(kt_g + (size_t)krow * 1024 + kc * 8, Ks + (size_t)chunk * 8);
                const int vrow = chunk >> 3;
                const int vc   = (chunk & 7) ^ (vrow & 7);
                load_lds16(vt_g + (size_t)vrow * 2048 + vc * 8, Vs + (size_t)chunk * 8);
            }
        }
        __syncthreads();   // barrier 1: DMA drained, tiles resident

        // ---- S^T = K * Q^T (K frags from swizzled LDS) ----
        fx4 sacc[4][2];
#pragma unroll
        for (int kt = 0; kt < 4; ++kt)
#pragma unroll
            for (int qt = 0; qt < 2; ++qt)
                sacc[kt][qt] = zero4;
#pragma unroll
        for (int kc = 0; kc < 4; ++kc)
#pragma unroll
            for (int kt = 0; kt < 4; ++kt) {
                bf16x8 kf = *(const bf16x8*)&Ks[(kt * 16 + l15) * 128 + (((kc * 4 + quad) ^ l15)) * 8];
#pragma unroll
                for (int qt = 0; qt < 2; ++qt)
                    sacc[kt][qt] = __builtin_amdgcn_mfma_f32_16x16x32_bf16(
                        kf, qf[qt][kc], sacc[kt][qt], 0, 0, 0);
            }

        // ---- causal mask on the diagonal block (log2-domain scores) ----
        if (kb == qb) {
#pragma unroll
            for (int kt = 0; kt < 4; ++kt)
#pragma unroll
                for (int qt = 0; qt < 2; ++qt)
#pragma unroll
                    for (int r = 0; r < 4; ++r) {
                        const int k_in = kt * 16 + quad * 4 + r;
                        const int q_in = rh * 32 + qt * 16 + l15;
                        if (q_in < k_in) sacc[kt][qt][r] = -1e30f;
                    }
        }

        // ---- no-max softmax: p = 2^s (no row reduce — l comes from MFMA) ----
#pragma unroll
        for (int kt = 0; kt < 4; ++kt)
#pragma unroll
            for (int qt = 0; qt < 2; ++qt)
#pragma unroll
                for (int r = 0; r < 4; ++r)
                    sacc[kt][qt][r] = exp2f(sacc[kt][qt][r]);

        // ---- in-register C->B transform (replaces P LDS overlay; verified
        //      bit-identical in passing R7/R9/R10 at this qt=2 width) ----
        bf16x8 pf[2][2];
#pragma unroll
        for (int qt = 0; qt < 2; ++qt)
#pragma unroll
            for (int kcg = 0; kcg < 2; ++kcg) {
                const unsigned a00 = cvt_pk_bf16(sacc[2*kcg  ][qt][0], sacc[2*kcg  ][qt][1]);
                const unsigned a01 = cvt_pk_bf16(sacc[2*kcg  ][qt][2], sacc[2*kcg  ][qt][3]);
                const unsigned a10 = cvt_pk_bf16(sacc[2*kcg+1][qt][0], sacc[2*kcg+1][qt][1]);
                const unsigned a11 = cvt_pk_bf16(sacc[2*kcg+1][qt][2], sacc[2*kcg+1][qt][3]);
                const u32x2 g00 = quad_gather(a00);
                const u32x2 g01 = quad_gather(a01);
                const u32x2 g10 = quad_gather(a10);
                const u32x2 g11 = quad_gather(a11);
                u32x4 pw;
                pw[0] = hi32 ? g10[0] : g00[0];
                pw[1] = hi32 ? g11[0] : g01[0];
                pw[2] = hi32 ? g10[1] : g00[1];
                pw[3] = hi32 ? g11[1] : g01[1];
                pf[qt][kcg] = __builtin_bit_cast(bf16x8, pw);
            }

        // ---- O^T += V^T * P^T ; l += ones * P^T (V frags from swizzled LDS) ----
#pragma unroll
        for (int kcg = 0; kcg < 2; ++kcg) {
#pragma unroll
            for (int dt = 0; dt < 8; ++dt) {
                bf16x8 vf = *(const bf16x8*)&Vs[(dt * 16 + l15) * 64 + (((kcg * 4 + quad) ^ (l15 & 7))) * 8];
#pragma unroll
                for (int qt = 0; qt < 2; ++qt)
                    oacc[dt][qt] = __builtin_amdgcn_mfma_f32_16x16x32_bf16(
                        vf, pf[qt][kcg], oacc[dt][qt], 0, 0, 0);
            }
#pragma unroll
            for (int qt = 0; qt < 2; ++qt)
                lacc[qt] = __builtin_amdgcn_mfma_f32_16x16x32_bf16(
                    ones, pf[qt][kcg], lacc[qt], 0, 0, 0);
        }

        __syncthreads();   // barrier 2: Ks/Vs reads done before next DMA
    }

    // ---- epilogue: each wave stores its own 32 rows ----
    const float inv0 = 1.0f / lacc[0][0];   // all rows of lacc are identical
    const float inv1 = 1.0f / lacc[1][0];
#pragma unroll
    for (int dt = 0; dt < 8; ++dt)
#pragma unroll
        for (int qt = 0; qt < 2; ++qt) {
            const float inv = qt ? inv1 : inv0;
            fx4 o = oacc[dt][qt] * inv;
            *(fx4*)(O + (size_t)(row0 + qt * 16 + l15) * 4096 + h * 128 + dt * 16 + quad * 4) = o;
        }
}

extern "C" void kernel_launch(void* const* d_in, const int* in_sizes, int n_in,
                              void* d_out, int out_size, void* d_ws, size_t ws_size,
                              hipStream_t stream) {
    (void)in_sizes; (void)n_in; (void)ws_size; (void)out_size;
    const float* q = (const float*)d_in[0];
    const float* k = (const float*)d_in[1];
    const float* v = (const float*)d_in[2];
    float* o = (float*)d_out;

    bf16_t* Kb = (bf16_t*)d_ws;                       // [2048][1024] bf16 = 4 MB
    bf16_t* VT = Kb + (size_t)2048 * 1024;            // [1024][2048] bf16 = 4 MB

    prep_kernel<<<dim3(512), dim3(256), 0, stream>>>(k, v, Kb, VT);
    bsfa_kernel<<<dim3(1024), dim3(128), 0, stream>>>(q, Kb, VT, o);
}